// Round 3
// baseline (147.064 us; speedup 1.0000x reference)
//
#include <hip/hip_runtime.h>
#include <hip/hip_bf16.h>
#include <stdint.h>

// Problem constants (fixed shapes from reference: B=4096, D=256, N=2B)
#define NROWS 8192
#define DDIM  256
#define BM    128
#define BN    128
#define BK    32
#define NTILE (NROWS / BM)              // 64 tile-rows
#define NTRI  (NTILE * (NTILE + 1) / 2) // 2080 upper-tri tiles
#define L2E   1.44269504088896340736f

typedef __attribute__((ext_vector_type(8))) short short8;
typedef __attribute__((ext_vector_type(4))) float f32x4;

typedef const __attribute__((address_space(1))) uint32_t glb_u32;
typedef __attribute__((address_space(3))) uint32_t lds_u32;

__device__ __forceinline__ void load_lds16(const unsigned short* g, unsigned short* l) {
  // 16B per lane, LDS dest = wave-uniform base + lane*16 (HW scatter)
  __builtin_amdgcn_global_load_lds((glb_u32*)g, (lds_u32*)l, 16, 0, 0);
}

__device__ __forceinline__ unsigned short f2bf(float x) {
  __hip_bfloat16 h = __float2bfloat16(x);
  return *reinterpret_cast<unsigned short*>(&h);
}

// Kernel 1: build bf16 concat(f), inv norms (fp32), int labels, zero S arrays.
__global__ void __launch_bounds__(256)
milnce_prep(const float* __restrict__ feat, const float* __restrict__ pos,
            const int* __restrict__ labels, unsigned short* __restrict__ fb,
            float* __restrict__ inv_w, int* __restrict__ lab,
            float* __restrict__ S_all, float* __restrict__ S_pos) {
  const int wave = threadIdx.x >> 6;
  const int lane = threadIdx.x & 63;
  const int row  = blockIdx.x * 4 + wave;   // grid 2048 blocks -> 8192 rows

  const float* src = (row < 4096) ? (feat + (size_t)row * DDIM)
                                  : (pos + (size_t)(row - 4096) * DDIM);
  float4 v = ((const float4*)src)[lane];    // 4 contiguous fp32 per lane

  ushort4 o;
  o.x = f2bf(v.x); o.y = f2bf(v.y); o.z = f2bf(v.z); o.w = f2bf(v.w);
  ((ushort4*)(fb + (size_t)row * DDIM))[lane] = o;

  float ss = v.x*v.x + v.y*v.y + v.z*v.z + v.w*v.w;
  #pragma unroll
  for (int m = 1; m < 64; m <<= 1) ss += __shfl_xor(ss, m, 64);
  if (lane == 0) inv_w[row] = 1.0f / sqrtf(ss);

  const int tid = blockIdx.x * 256 + threadIdx.x;
  if (tid < NROWS) {
    lab[tid]   = labels[tid & 4095];  // concat duplicates labels
    S_all[tid] = 0.0f;
    S_pos[tid] = 0.0f;
  }
}

// Kernel 2: fused f@f^T (bf16 MFMA) + exp(z-10) masked sums, UPPER-TRI tiles only.
// z is symmetric, so tile (j,i) == tile (i,j)^T. We compute only tiles with
// bj >= bi (2080 of 4096). Off-diagonal tiles contribute:
//   column sums -> S[col strip bj]   (this tile's own contribution)
//   row sums    -> S[row strip bi]   (== column sums of the skipped (bj,bi) tile)
// Diagonal tiles (bi==bj) contribute column sums once (that sub-block is itself
// symmetric, and its diagonal entries are masked to 0).
// LDS k-slices are XOR-swizzled (round 2): fragment ds_read_b128 spreads over
// 8 bank-start positions -> 2-way aliasing = free.
__global__ void __launch_bounds__(256)
milnce_gemm(const unsigned short* __restrict__ fb, const float* __restrict__ inv_w,
            const int* __restrict__ lab, float* __restrict__ S_all,
            float* __restrict__ S_pos) {
  __shared__ unsigned short ldsA[BM * BK];  // 8 KB
  __shared__ unsigned short ldsB[BN * BK];  // 8 KB

  // Decode linear tile id -> upper-tri (bi, bj), row-major over rows bi.
  int t = blockIdx.x;
  int bi = 0, rem = NTILE;
  while (t >= rem) { t -= rem; ++bi; --rem; }
  const int bj = bi + t;

  const int tid  = threadIdx.x;
  const int wave = tid >> 6;
  const int lane = tid & 63;
  const int quad = lane >> 4;
  const int l15  = lane & 15;
  const int wm   = wave >> 1;   // 2x2 wave grid over 128x128
  const int wn   = wave & 1;
  const int rowBase = bi * BM;
  const int colBase = bj * BN;

  f32x4 acc[4][4];
  #pragma unroll
  for (int i = 0; i < 4; ++i)
    #pragma unroll
    for (int j = 0; j < 4; ++j) acc[i][j] = (f32x4){0.f, 0.f, 0.f, 0.f};

  // Staging: slot s (0..511) is 16B at LDS offset s*16; row = s>>2.
  // Swizzle: slot s holds global k-slice gsl = (s&3) ^ ((s>>3)&3).
  const int s0 = wave * 64 + lane;       // load 0
  const int s1 = s0 + 256;               // load 1
  const int r0 = s0 >> 2, g0 = (s0 & 3) ^ ((s0 >> 3) & 3);
  const int r1 = s1 >> 2, g1 = (s1 & 3) ^ ((s1 >> 3) & 3);
  const unsigned short* gA0 = fb + (size_t)(rowBase + r0) * DDIM + g0 * 8;
  const unsigned short* gA1 = fb + (size_t)(rowBase + r1) * DDIM + g1 * 8;
  const unsigned short* gB0 = fb + (size_t)(colBase + r0) * DDIM + g0 * 8;
  const unsigned short* gB1 = fb + (size_t)(colBase + r1) * DDIM + g1 * 8;
  unsigned short* lA0 = ldsA + (size_t)(wave * 64) * 8;          // wave-uniform bases
  unsigned short* lA1 = ldsA + (size_t)(wave * 64 + 256) * 8;
  unsigned short* lB0 = ldsB + (size_t)(wave * 64) * 8;
  unsigned short* lB1 = ldsB + (size_t)(wave * 64 + 256) * 8;

  // Reader swizzle: global slice `quad` of row r lives at LDS slice
  // xsl = quad ^ ((r>>1)&3) = quad ^ ((l15>>1)&3).
  const int xsl = quad ^ ((l15 >> 1) & 3);

  #pragma unroll
  for (int kt = 0; kt < DDIM / BK; ++kt) {
    const int ko = kt * BK;
    __syncthreads();                       // protect LDS reuse
    load_lds16(gA0 + ko, lA0);
    load_lds16(gA1 + ko, lA1);
    load_lds16(gB0 + ko, lB0);
    load_lds16(gB1 + ko, lB1);
    __syncthreads();                       // drains vmcnt (compiler-inserted)

    short8 a[4], b[4];
    #pragma unroll
    for (int mi = 0; mi < 4; ++mi)
      a[mi] = *(const short8*)&ldsA[(wm * 64 + mi * 16 + l15) * BK + xsl * 8];
    #pragma unroll
    for (int ni = 0; ni < 4; ++ni)
      b[ni] = *(const short8*)&ldsB[(wn * 64 + ni * 16 + l15) * BK + xsl * 8];

    #pragma unroll
    for (int mi = 0; mi < 4; ++mi)
      #pragma unroll
      for (int ni = 0; ni < 4; ++ni)
        acc[mi][ni] = __builtin_amdgcn_mfma_f32_16x16x32_bf16(a[mi], b[ni], acc[mi][ni], 0, 0, 0);
  }

  // Epilogue. C/D layout (16x16x32): col = lane&15, row = quad*4 + reg.
  // e = exp2(z*L2E - 10*L2E), diag masked to 0.
  const float SHIFT = 10.0f * L2E;
  float cf[4]; int cl[4], colg[4];
  #pragma unroll
  for (int ni = 0; ni < 4; ++ni) {
    colg[ni] = colBase + wn * 64 + ni * 16 + l15;
    cf[ni]   = inv_w[colg[ni]] * (10.0f * L2E);
    cl[ni]   = lab[colg[ni]];
  }

  const bool offdiag = (bi != bj);

  float ca[4] = {0.f, 0.f, 0.f, 0.f};   // column sums (all)
  float cp[4] = {0.f, 0.f, 0.f, 0.f};   // column sums (pos)
  float ra[4][4];                        // row partials (all), [mi][r]
  float rp[4][4];                        // row partials (pos)
  #pragma unroll
  for (int mi = 0; mi < 4; ++mi)
    #pragma unroll
    for (int r = 0; r < 4; ++r) { ra[mi][r] = 0.f; rp[mi][r] = 0.f; }

  #pragma unroll
  for (int mi = 0; mi < 4; ++mi) {
    #pragma unroll
    for (int r = 0; r < 4; ++r) {
      const int rowg = rowBase + wm * 64 + mi * 16 + quad * 4 + r;
      const float rf = inv_w[rowg];
      const int   rl = lab[rowg];
      #pragma unroll
      for (int ni = 0; ni < 4; ++ni) {
        float e = exp2f(acc[mi][ni][r] * rf * cf[ni] - SHIFT);
        if (rowg == colg[ni]) e = 0.f;   // diagonal excluded from both sums
        const bool same = (rl == cl[ni]);
        ca[ni] += e;
        if (same) cp[ni] += e;
        ra[mi][r] += e;
        if (same) rp[mi][r] += e;
      }
    }
  }

  // Column reduction: 2 shfl across quads, commit from quad 0.
  #pragma unroll
  for (int ni = 0; ni < 4; ++ni) {
    ca[ni] += __shfl_xor(ca[ni], 16, 64);
    ca[ni] += __shfl_xor(ca[ni], 32, 64);
    cp[ni] += __shfl_xor(cp[ni], 16, 64);
    cp[ni] += __shfl_xor(cp[ni], 32, 64);
  }
  if (quad == 0) {
    #pragma unroll
    for (int ni = 0; ni < 4; ++ni) {
      atomicAdd(&S_all[colg[ni]], ca[ni]);
      atomicAdd(&S_pos[colg[ni]], cp[ni]);
    }
  }

  // Row reduction (off-diagonal tiles only): butterfly over the 16 l15 lanes
  // within each quad; lane l15 == mi*4+r commits row (mi,quad,r).
  if (offdiag) {
    #pragma unroll
    for (int mi = 0; mi < 4; ++mi) {
      #pragma unroll
      for (int r = 0; r < 4; ++r) {
        float va = ra[mi][r];
        va += __shfl_xor(va, 1, 64); va += __shfl_xor(va, 2, 64);
        va += __shfl_xor(va, 4, 64); va += __shfl_xor(va, 8, 64);
        float vp = rp[mi][r];
        vp += __shfl_xor(vp, 1, 64); vp += __shfl_xor(vp, 2, 64);
        vp += __shfl_xor(vp, 4, 64); vp += __shfl_xor(vp, 8, 64);
        if (l15 == mi * 4 + r) {
          const int rowg = rowBase + wm * 64 + mi * 16 + quad * 4 + r;
          atomicAdd(&S_all[rowg], va);
          atomicAdd(&S_pos[rowg], vp);
        }
      }
    }
  }
}

// Kernel 3: loss = sum_i log(S_all[i]) - log(S_pos[i])  (the +10 shifts cancel)
__global__ void __launch_bounds__(1024)
milnce_final(const float* __restrict__ S_all, const float* __restrict__ S_pos,
             float* __restrict__ out) {
  __shared__ float red[16];
  float s = 0.f;
  for (int i = threadIdx.x; i < NROWS; i += 1024)
    s += logf(S_all[i]) - logf(S_pos[i]);
  #pragma unroll
  for (int m = 1; m < 64; m <<= 1) s += __shfl_xor(s, m, 64);
  const int wave = threadIdx.x >> 6;
  if ((threadIdx.x & 63) == 0) red[wave] = s;
  __syncthreads();
  if (threadIdx.x == 0) {
    float t = 0.f;
    #pragma unroll
    for (int i = 0; i < 16; ++i) t += red[i];
    out[0] = t;
  }
}

extern "C" void kernel_launch(void* const* d_in, const int* in_sizes, int n_in,
                              void* d_out, int out_size, void* d_ws, size_t ws_size,
                              hipStream_t stream) {
  const float* feat   = (const float*)d_in[0];
  const float* pos    = (const float*)d_in[1];
  const int*   labels = (const int*)d_in[2];

  char* ws = (char*)d_ws;
  unsigned short* fb    = (unsigned short*)ws;                       // 4 MB bf16 concat
  float*          inv_w = (float*)(ws + 4u * 1024 * 1024);           // 32 KB
  int*            lab   = (int*)  (ws + 4u * 1024 * 1024 + 32 * 1024);
  float*          S_all = (float*)(ws + 4u * 1024 * 1024 + 64 * 1024);
  float*          S_pos = (float*)(ws + 4u * 1024 * 1024 + 96 * 1024);
  float*          out   = (float*)d_out;

  hipLaunchKernelGGL(milnce_prep, dim3(NROWS / 4), dim3(256), 0, stream,
                     feat, pos, labels, fb, inv_w, lab, S_all, S_pos);
  hipLaunchKernelGGL(milnce_gemm, dim3(NTRI), dim3(256), 0, stream,
                     fb, inv_w, lab, S_all, S_pos);
  hipLaunchKernelGGL(milnce_final, dim3(1), dim3(1024), 0, stream,
                     S_all, S_pos, out);
}

// Round 4
// 123.260 us; speedup vs baseline: 1.1931x; 1.1931x over previous
//
#include <hip/hip_runtime.h>
#include <hip/hip_bf16.h>
#include <stdint.h>

// Problem constants (fixed shapes from reference: B=4096, D=256, N=2B)
#define NROWS 8192
#define DDIM  256
#define BM    128
#define BN    128
#define BK    32
#define NTILE (NROWS / BM)              // 64 tile-rows
#define NTRI  (NTILE * (NTILE + 1) / 2) // 2080 upper-tri tiles
#define L2E   1.44269504088896340736f

typedef __attribute__((ext_vector_type(8))) short short8;
typedef __attribute__((ext_vector_type(4))) float f32x4;

typedef const __attribute__((address_space(1))) uint32_t glb_u32;
typedef __attribute__((address_space(3))) uint32_t lds_u32;

__device__ __forceinline__ void load_lds16(const unsigned short* g, unsigned short* l) {
  // 16B per lane, LDS dest = wave-uniform base + lane*16 (HW scatter)
  __builtin_amdgcn_global_load_lds((glb_u32*)g, (lds_u32*)l, 16, 0, 0);
}

__device__ __forceinline__ unsigned short f2bf(float x) {
  __hip_bfloat16 h = __float2bfloat16(x);
  return *reinterpret_cast<unsigned short*>(&h);
}

__device__ __forceinline__ int bitrev4(int x) {
  return ((x & 1) << 3) | ((x & 2) << 1) | ((x & 4) >> 1) | ((x & 8) >> 3);
}

// Kernel 1: build bf16 concat(f), inv norms (fp32), int labels, zero S arrays.
__global__ void __launch_bounds__(256)
milnce_prep(const float* __restrict__ feat, const float* __restrict__ pos,
            const int* __restrict__ labels, unsigned short* __restrict__ fb,
            float* __restrict__ inv_w, int* __restrict__ lab,
            float* __restrict__ S_all, float* __restrict__ S_pos) {
  const int wave = threadIdx.x >> 6;
  const int lane = threadIdx.x & 63;
  const int row  = blockIdx.x * 4 + wave;   // grid 2048 blocks -> 8192 rows

  const float* src = (row < 4096) ? (feat + (size_t)row * DDIM)
                                  : (pos + (size_t)(row - 4096) * DDIM);
  float4 v = ((const float4*)src)[lane];    // 4 contiguous fp32 per lane

  ushort4 o;
  o.x = f2bf(v.x); o.y = f2bf(v.y); o.z = f2bf(v.z); o.w = f2bf(v.w);
  ((ushort4*)(fb + (size_t)row * DDIM))[lane] = o;

  float ss = v.x*v.x + v.y*v.y + v.z*v.z + v.w*v.w;
  #pragma unroll
  for (int m = 1; m < 64; m <<= 1) ss += __shfl_xor(ss, m, 64);
  if (lane == 0) inv_w[row] = 1.0f / sqrtf(ss);

  const int tid = blockIdx.x * 256 + threadIdx.x;
  if (tid < NROWS) {
    lab[tid]   = labels[tid & 4095];  // concat duplicates labels
    S_all[tid] = 0.0f;
    S_pos[tid] = 0.0f;
  }
}

// Kernel 2: fused f@f^T (bf16 MFMA) + exp(z-10) masked sums, UPPER-TRI tiles only.
// Tiles enumerated by DIAGONAL d = bj-bi: all tiles on one diagonal touch
// distinct row strips and distinct column strips, so concurrently-resident
// blocks don't contend on the same S cachelines (round-3 post-mortem: the
// row-major triangular order made ~64 consecutive blocks hammer one strip;
// WRITE_SIZE showed each scattered atomic costs a 64B HBM line op).
// Commits are single 64-lane fully-coalesced atomics built via register
// reduce-scatter + one bpermute, not masked butterflies.
__global__ void __launch_bounds__(256)
milnce_gemm(const unsigned short* __restrict__ fb, const float* __restrict__ inv_w,
            const int* __restrict__ lab, float* __restrict__ S_all,
            float* __restrict__ S_pos) {
  __shared__ unsigned short ldsA[BM * BK];  // 8 KB
  __shared__ unsigned short ldsB[BN * BK];  // 8 KB

  // Decode linear tile id -> (bi, bj) along diagonals: d = bj - bi = 0..63,
  // diagonal d has 64-d tiles.
  int t = blockIdx.x, d = 0, rem = NTILE;
  while (t >= rem) { t -= rem; ++d; --rem; }
  const int bi = t, bj = t + d;

  const int tid  = threadIdx.x;
  const int wave = tid >> 6;
  const int lane = tid & 63;
  const int quad = lane >> 4;
  const int l15  = lane & 15;
  const int wm   = wave >> 1;   // 2x2 wave grid over 128x128
  const int wn   = wave & 1;
  const int rowBase = bi * BM;
  const int colBase = bj * BN;

  f32x4 acc[4][4];
  #pragma unroll
  for (int i = 0; i < 4; ++i)
    #pragma unroll
    for (int j = 0; j < 4; ++j) acc[i][j] = (f32x4){0.f, 0.f, 0.f, 0.f};

  // Staging: slot s (0..511) is 16B at LDS offset s*16; row = s>>2.
  // Swizzle: slot s holds global k-slice gsl = (s&3) ^ ((s>>3)&3).
  const int s0 = wave * 64 + lane;       // load 0
  const int s1 = s0 + 256;               // load 1
  const int r0 = s0 >> 2, g0 = (s0 & 3) ^ ((s0 >> 3) & 3);
  const int r1 = s1 >> 2, g1 = (s1 & 3) ^ ((s1 >> 3) & 3);
  const unsigned short* gA0 = fb + (size_t)(rowBase + r0) * DDIM + g0 * 8;
  const unsigned short* gA1 = fb + (size_t)(rowBase + r1) * DDIM + g1 * 8;
  const unsigned short* gB0 = fb + (size_t)(colBase + r0) * DDIM + g0 * 8;
  const unsigned short* gB1 = fb + (size_t)(colBase + r1) * DDIM + g1 * 8;
  unsigned short* lA0 = ldsA + (size_t)(wave * 64) * 8;          // wave-uniform bases
  unsigned short* lA1 = ldsA + (size_t)(wave * 64 + 256) * 8;
  unsigned short* lB0 = ldsB + (size_t)(wave * 64) * 8;
  unsigned short* lB1 = ldsB + (size_t)(wave * 64 + 256) * 8;

  // Reader swizzle: global slice `quad` of row r lives at LDS slice
  // xsl = quad ^ ((r>>1)&3) = quad ^ ((l15>>1)&3).
  const int xsl = quad ^ ((l15 >> 1) & 3);

  #pragma unroll
  for (int kt = 0; kt < DDIM / BK; ++kt) {
    const int ko = kt * BK;
    __syncthreads();                       // protect LDS reuse
    load_lds16(gA0 + ko, lA0);
    load_lds16(gA1 + ko, lA1);
    load_lds16(gB0 + ko, lB0);
    load_lds16(gB1 + ko, lB1);
    __syncthreads();                       // drains vmcnt (compiler-inserted)

    short8 a[4], b[4];
    #pragma unroll
    for (int mi = 0; mi < 4; ++mi)
      a[mi] = *(const short8*)&ldsA[(wm * 64 + mi * 16 + l15) * BK + xsl * 8];
    #pragma unroll
    for (int ni = 0; ni < 4; ++ni)
      b[ni] = *(const short8*)&ldsB[(wn * 64 + ni * 16 + l15) * BK + xsl * 8];

    #pragma unroll
    for (int mi = 0; mi < 4; ++mi)
      #pragma unroll
      for (int ni = 0; ni < 4; ++ni)
        acc[mi][ni] = __builtin_amdgcn_mfma_f32_16x16x32_bf16(a[mi], b[ni], acc[mi][ni], 0, 0, 0);
  }

  // Epilogue. C/D layout (16x16x32): col = lane&15, row = quad*4 + reg.
  // e = exp2(z*L2E - 10*L2E), diag masked to 0.
  const float SHIFT = 10.0f * L2E;
  float cf[4]; int cl[4], colg[4];
  #pragma unroll
  for (int ni = 0; ni < 4; ++ni) {
    colg[ni] = colBase + wn * 64 + ni * 16 + l15;
    cf[ni]   = inv_w[colg[ni]] * (10.0f * L2E);
    cl[ni]   = lab[colg[ni]];
  }

  const bool offdiag = (bi != bj);

  float ca[4] = {0.f, 0.f, 0.f, 0.f};   // column partials (all), [ni]
  float cp[4] = {0.f, 0.f, 0.f, 0.f};   // column partials (pos)
  float ra[16], rp[16];                  // row partials, idx = mi*4+r
  #pragma unroll
  for (int i = 0; i < 16; ++i) { ra[i] = 0.f; rp[i] = 0.f; }

  #pragma unroll
  for (int mi = 0; mi < 4; ++mi) {
    #pragma unroll
    for (int r = 0; r < 4; ++r) {
      const int rowg = rowBase + wm * 64 + mi * 16 + quad * 4 + r;
      const float rf = inv_w[rowg];
      const int   rl = lab[rowg];
      #pragma unroll
      for (int ni = 0; ni < 4; ++ni) {
        float e = exp2f(acc[mi][ni][r] * rf * cf[ni] - SHIFT);
        if (rowg == colg[ni]) e = 0.f;   // diagonal excluded from both sums
        const bool same = (rl == cl[ni]);
        ca[ni] += e;
        if (same) cp[ni] += e;
        ra[mi * 4 + r] += e;
        if (same) rp[mi * 4 + r] += e;
      }
    }
  }

  // --- Column commit: reduce-scatter over quads (3 shfl/array), then one
  // bpermute to lane==column order, then ONE 64-lane coalesced atomic. ---
  {
    // step m=16 (quad bit0 selects ni bit1): 4 -> 2 values
    const bool u0 = lane & 16;
    float m0, o0;
    m0 = u0 ? ca[2] : ca[0]; o0 = u0 ? ca[0] : ca[2];
    ca[0] = m0 + __shfl_xor(o0, 16, 64);
    m0 = u0 ? ca[3] : ca[1]; o0 = u0 ? ca[1] : ca[3];
    ca[1] = m0 + __shfl_xor(o0, 16, 64);
    m0 = u0 ? cp[2] : cp[0]; o0 = u0 ? cp[0] : cp[2];
    cp[0] = m0 + __shfl_xor(o0, 16, 64);
    m0 = u0 ? cp[3] : cp[1]; o0 = u0 ? cp[1] : cp[3];
    cp[1] = m0 + __shfl_xor(o0, 16, 64);
    // step m=32 (quad bit1 selects ni bit0): 2 -> 1
    const bool u1 = lane & 32;
    m0 = u1 ? ca[1] : ca[0]; o0 = u1 ? ca[0] : ca[1];
    ca[0] = m0 + __shfl_xor(o0, 32, 64);
    m0 = u1 ? cp[1] : cp[0]; o0 = u1 ? cp[0] : cp[1];
    cp[0] = m0 + __shfl_xor(o0, 32, 64);
    // lane (q, l15) now owns column ni = bitrev2(q): src for lane t is
    // lane bitrev2(t>>4)*16 + (t&15)
    const int srcC = ((((lane >> 4) & 1) << 1) | ((lane >> 5) & 1)) * 16 + l15;
    float colA = __shfl(ca[0], srcC, 64);
    float colP = __shfl(cp[0], srcC, 64);
    atomicAdd(&S_all[colBase + wn * 64 + lane], colA);
    atomicAdd(&S_pos[colBase + wn * 64 + lane], colP);
  }

  // --- Row commit (off-diagonal only; rows of this tile == columns of the
  // skipped transposed tile): reduce-scatter over the 16 l15 lanes
  // (15 shfl/array), bpermute to lane==row order, ONE coalesced atomic. ---
  if (offdiag) {
    int nv = 16;
    #pragma unroll
    for (int m = 1; m <= 8; m <<= 1) {
      nv >>= 1;
      const bool up = (l15 & m);
      #pragma unroll
      for (int i = 0; i < nv; ++i) {
        float mine = up ? ra[i + nv] : ra[i];
        float oth  = up ? ra[i]      : ra[i + nv];
        ra[i] = mine + __shfl_xor(oth, m, 64);
        mine = up ? rp[i + nv] : rp[i];
        oth  = up ? rp[i]      : rp[i + nv];
        rp[i] = mine + __shfl_xor(oth, m, 64);
      }
    }
    // lane (q, l15) now owns idx = bitrev4(l15) -> row mi*16 + q*4 + r with
    // mi*4+r = bitrev4(l15). Lane t wants row t: mi=(t>>4)&3, q=(t>>2)&3,
    // r=t&3 -> src lane = q*16 + bitrev4(mi*4+r).
    const int srcR = ((lane >> 2) & 3) * 16 + bitrev4(((lane >> 4) & 3) * 4 + (lane & 3));
    float rowA = __shfl(ra[0], srcR, 64);
    float rowP = __shfl(rp[0], srcR, 64);
    atomicAdd(&S_all[rowBase + wm * 64 + lane], rowA);
    atomicAdd(&S_pos[rowBase + wm * 64 + lane], rowP);
  }
}

// Kernel 3: loss = sum_i log(S_all[i]) - log(S_pos[i])  (the +10 shifts cancel)
__global__ void __launch_bounds__(1024)
milnce_final(const float* __restrict__ S_all, const float* __restrict__ S_pos,
             float* __restrict__ out) {
  __shared__ float red[16];
  float s = 0.f;
  for (int i = threadIdx.x; i < NROWS; i += 1024)
    s += logf(S_all[i]) - logf(S_pos[i]);
  #pragma unroll
  for (int m = 1; m < 64; m <<= 1) s += __shfl_xor(s, m, 64);
  const int wave = threadIdx.x >> 6;
  if ((threadIdx.x & 63) == 0) red[wave] = s;
  __syncthreads();
  if (threadIdx.x == 0) {
    float t = 0.f;
    #pragma unroll
    for (int i = 0; i < 16; ++i) t += red[i];
    out[0] = t;
  }
}

extern "C" void kernel_launch(void* const* d_in, const int* in_sizes, int n_in,
                              void* d_out, int out_size, void* d_ws, size_t ws_size,
                              hipStream_t stream) {
  const float* feat   = (const float*)d_in[0];
  const float* pos    = (const float*)d_in[1];
  const int*   labels = (const int*)d_in[2];

  char* ws = (char*)d_ws;
  unsigned short* fb    = (unsigned short*)ws;                       // 4 MB bf16 concat
  float*          inv_w = (float*)(ws + 4u * 1024 * 1024);           // 32 KB
  int*            lab   = (int*)  (ws + 4u * 1024 * 1024 + 32 * 1024);
  float*          S_all = (float*)(ws + 4u * 1024 * 1024 + 64 * 1024);
  float*          S_pos = (float*)(ws + 4u * 1024 * 1024 + 96 * 1024);
  float*          out   = (float*)d_out;

  hipLaunchKernelGGL(milnce_prep, dim3(NROWS / 4), dim3(256), 0, stream,
                     feat, pos, labels, fb, inv_w, lab, S_all, S_pos);
  hipLaunchKernelGGL(milnce_gemm, dim3(NTRI), dim3(256), 0, stream,
                     fb, inv_w, lab, S_all, S_pos);
  hipLaunchKernelGGL(milnce_final, dim3(1), dim3(1024), 0, stream,
                     S_all, S_pos, out);
}

// Round 5
// 106.143 us; speedup vs baseline: 1.3855x; 1.1613x over previous
//
#include <hip/hip_runtime.h>
#include <hip/hip_bf16.h>
#include <stdint.h>

// Problem constants (fixed shapes from reference: B=4096, D=256, N=2B)
#define NROWS 8192
#define DDIM  256
#define BM    128
#define BN    128
#define BK    32
#define NTILE (NROWS / BM)              // 64 tile-rows
#define NTRI  (NTILE * (NTILE + 1) / 2) // 2080 upper-tri tiles
#define L2E   1.44269504088896340736f

// LDS epilogue layout (aliases the staging buffers after the K-loop):
//   colAP: float2 [128 cols][5 slots]  (4 quad partials + 1 pad) = 5120 B
//          stride 10 dwords -> 16 lanes x b64 cover all 32 banks once.
//   rowAP: float2 [128 rows][18 slots] (16 lane partials + 2 pad) = 18432 B
//          stride 36 dwords == 16-bank offset -> uniform 2-way (free);
//          36 dw = 144 B keeps rows 16B-aligned for b128 reads.
#define COL_STRIDE2 5
#define ROW_STRIDE2 18
#define ROWAP_OFF   5120
#define SMEM_BYTES  (ROWAP_OFF + 128 * ROW_STRIDE2 * 8)  // 23552

typedef __attribute__((ext_vector_type(8))) short short8;
typedef __attribute__((ext_vector_type(4))) float f32x4;

typedef const __attribute__((address_space(1))) uint32_t glb_u32;
typedef __attribute__((address_space(3))) uint32_t lds_u32;

__device__ __forceinline__ void load_lds16(const unsigned short* g, unsigned short* l) {
  // 16B per lane, LDS dest = wave-uniform base + lane*16 (HW scatter)
  __builtin_amdgcn_global_load_lds((glb_u32*)g, (lds_u32*)l, 16, 0, 0);
}

__device__ __forceinline__ unsigned short f2bf(float x) {
  __hip_bfloat16 h = __float2bfloat16(x);
  return *reinterpret_cast<unsigned short*>(&h);
}

// Kernel 1: build bf16 concat(f), inv norms (fp32), int labels, zero S arrays.
__global__ void __launch_bounds__(256)
milnce_prep(const float* __restrict__ feat, const float* __restrict__ pos,
            const int* __restrict__ labels, unsigned short* __restrict__ fb,
            float* __restrict__ inv_w, int* __restrict__ lab,
            float* __restrict__ S_all, float* __restrict__ S_pos) {
  const int wave = threadIdx.x >> 6;
  const int lane = threadIdx.x & 63;
  const int row  = blockIdx.x * 4 + wave;   // grid 2048 blocks -> 8192 rows

  const float* src = (row < 4096) ? (feat + (size_t)row * DDIM)
                                  : (pos + (size_t)(row - 4096) * DDIM);
  float4 v = ((const float4*)src)[lane];    // 4 contiguous fp32 per lane

  ushort4 o;
  o.x = f2bf(v.x); o.y = f2bf(v.y); o.z = f2bf(v.z); o.w = f2bf(v.w);
  ((ushort4*)(fb + (size_t)row * DDIM))[lane] = o;

  float ss = v.x*v.x + v.y*v.y + v.z*v.z + v.w*v.w;
  #pragma unroll
  for (int m = 1; m < 64; m <<= 1) ss += __shfl_xor(ss, m, 64);
  if (lane == 0) inv_w[row] = 1.0f / sqrtf(ss);

  const int tid = blockIdx.x * 256 + threadIdx.x;
  if (tid < NROWS) {
    lab[tid]   = labels[tid & 4095];  // concat duplicates labels
    S_all[tid] = 0.0f;
    S_pos[tid] = 0.0f;
  }
}

// Kernel 2: fused f@f^T (bf16 MFMA) + exp(z-10) masked sums, UPPER-TRI tiles,
// diagonal-order enumeration (no S-cacheline contention between resident
// blocks). Epilogue reduces via LDS scratch (aliased over the staging tiles)
// instead of register reduce-scatter: round-4 post-mortem showed the 32-reg
// row-partial arrays + 60-shfl butterfly made the kernel VALU-bound
// (VALUBusy 60%) and spilled (FETCH +5MB).
__global__ void __launch_bounds__(256)
milnce_gemm(const unsigned short* __restrict__ fb, const float* __restrict__ inv_w,
            const int* __restrict__ lab, float* __restrict__ S_all,
            float* __restrict__ S_pos) {
  __shared__ __align__(16) char smem[SMEM_BYTES];
  unsigned short* ldsA = (unsigned short*)smem;            // 8 KB staging
  unsigned short* ldsB = (unsigned short*)(smem + 8192);   // 8 KB staging
  float2* colAP = (float2*)smem;                           // epilogue (aliased)
  float2* rowAP = (float2*)(smem + ROWAP_OFF);

  // Decode linear tile id -> (bi, bj) along diagonals: d = bj - bi = 0..63,
  // diagonal d has 64-d tiles.
  int t = blockIdx.x, d = 0, rem = NTILE;
  while (t >= rem) { t -= rem; ++d; --rem; }
  const int bi = t, bj = t + d;

  const int tid  = threadIdx.x;
  const int wave = tid >> 6;
  const int lane = tid & 63;
  const int quad = lane >> 4;
  const int l15  = lane & 15;
  const int wm   = wave >> 1;   // 2x2 wave grid over 128x128
  const int wn   = wave & 1;
  const int rowBase = bi * BM;
  const int colBase = bj * BN;

  f32x4 acc[4][4];
  #pragma unroll
  for (int i = 0; i < 4; ++i)
    #pragma unroll
    for (int j = 0; j < 4; ++j) acc[i][j] = (f32x4){0.f, 0.f, 0.f, 0.f};

  // Staging: slot s (0..511) is 16B at LDS offset s*16; row = s>>2.
  // Swizzle: slot s holds global k-slice gsl = (s&3) ^ ((s>>3)&3).
  const int s0 = wave * 64 + lane;       // load 0
  const int s1 = s0 + 256;               // load 1
  const int r0 = s0 >> 2, g0 = (s0 & 3) ^ ((s0 >> 3) & 3);
  const int r1 = s1 >> 2, g1 = (s1 & 3) ^ ((s1 >> 3) & 3);
  const unsigned short* gA0 = fb + (size_t)(rowBase + r0) * DDIM + g0 * 8;
  const unsigned short* gA1 = fb + (size_t)(rowBase + r1) * DDIM + g1 * 8;
  const unsigned short* gB0 = fb + (size_t)(colBase + r0) * DDIM + g0 * 8;
  const unsigned short* gB1 = fb + (size_t)(colBase + r1) * DDIM + g1 * 8;
  unsigned short* lA0 = ldsA + (size_t)(wave * 64) * 8;          // wave-uniform bases
  unsigned short* lA1 = ldsA + (size_t)(wave * 64 + 256) * 8;
  unsigned short* lB0 = ldsB + (size_t)(wave * 64) * 8;
  unsigned short* lB1 = ldsB + (size_t)(wave * 64 + 256) * 8;

  // Reader swizzle: global slice `quad` of row r lives at LDS slice
  // xsl = quad ^ ((r>>1)&3) = quad ^ ((l15>>1)&3).
  const int xsl = quad ^ ((l15 >> 1) & 3);

  #pragma unroll
  for (int kt = 0; kt < DDIM / BK; ++kt) {
    const int ko = kt * BK;
    __syncthreads();                       // protect LDS reuse
    load_lds16(gA0 + ko, lA0);
    load_lds16(gA1 + ko, lA1);
    load_lds16(gB0 + ko, lB0);
    load_lds16(gB1 + ko, lB1);
    __syncthreads();                       // drains vmcnt (compiler-inserted)

    short8 a[4], b[4];
    #pragma unroll
    for (int mi = 0; mi < 4; ++mi)
      a[mi] = *(const short8*)&ldsA[(wm * 64 + mi * 16 + l15) * BK + xsl * 8];
    #pragma unroll
    for (int ni = 0; ni < 4; ++ni)
      b[ni] = *(const short8*)&ldsB[(wn * 64 + ni * 16 + l15) * BK + xsl * 8];

    #pragma unroll
    for (int mi = 0; mi < 4; ++mi)
      #pragma unroll
      for (int ni = 0; ni < 4; ++ni)
        acc[mi][ni] = __builtin_amdgcn_mfma_f32_16x16x32_bf16(a[mi], b[ni], acc[mi][ni], 0, 0, 0);
  }

  __syncthreads();   // staging LDS is dead; safe to alias with epilogue scratch

  // Epilogue. C/D layout (16x16x32): col = lane&15, row = quad*4 + reg.
  // e = exp2(z*L2E - 10*L2E); (e, e_pos) packed as float2 -> v_pk_add_f32.
  const float SHIFT = 10.0f * L2E;
  float cf[4]; int cl[4], colg[4];
  #pragma unroll
  for (int ni = 0; ni < 4; ++ni) {
    colg[ni] = colBase + wn * 64 + ni * 16 + l15;
    cf[ni]   = inv_w[colg[ni]] * (10.0f * L2E);
    cl[ni]   = lab[colg[ni]];
  }

  const bool offdiag = (bi != bj);

  float2 capk[4] = {{0.f,0.f},{0.f,0.f},{0.f,0.f},{0.f,0.f}};

  if (offdiag) {
    #pragma unroll
    for (int mi = 0; mi < 4; ++mi) {
      const int rbase = wm * 64 + mi * 16 + quad * 4;
      const float4 rf4 = *(const float4*)&inv_w[rowBase + rbase];
      const int4   rl4 = *(const int4*)&lab[rowBase + rbase];
      #pragma unroll
      for (int r = 0; r < 4; ++r) {
        const float rf = (r == 0) ? rf4.x : (r == 1) ? rf4.y : (r == 2) ? rf4.z : rf4.w;
        const int   rl = (r == 0) ? rl4.x : (r == 1) ? rl4.y : (r == 2) ? rl4.z : rl4.w;
        float sx = 0.f, sy = 0.f;
        #pragma unroll
        for (int ni = 0; ni < 4; ++ni) {
          float e  = exp2f(acc[mi][ni][r] * rf * cf[ni] - SHIFT);
          float ep = (rl == cl[ni]) ? e : 0.f;   // no diagonal here (bi != bj)
          capk[ni].x += e; capk[ni].y += ep;
          sx += e; sy += ep;
        }
        rowAP[(rbase + r) * ROW_STRIDE2 + wn * 16 + l15] = make_float2(sx, sy);
      }
    }
  } else {
    #pragma unroll
    for (int mi = 0; mi < 4; ++mi) {
      const int rbase = wm * 64 + mi * 16 + quad * 4;
      const float4 rf4 = *(const float4*)&inv_w[rowBase + rbase];
      const int4   rl4 = *(const int4*)&lab[rowBase + rbase];
      #pragma unroll
      for (int r = 0; r < 4; ++r) {
        const float rf = (r == 0) ? rf4.x : (r == 1) ? rf4.y : (r == 2) ? rf4.z : rf4.w;
        const int   rl = (r == 0) ? rl4.x : (r == 1) ? rl4.y : (r == 2) ? rl4.z : rl4.w;
        const int rowg = rowBase + rbase + r;
        #pragma unroll
        for (int ni = 0; ni < 4; ++ni) {
          float e = exp2f(acc[mi][ni][r] * rf * cf[ni] - SHIFT);
          if (rowg == colg[ni]) e = 0.f;         // mask diagonal entries
          float ep = (rl == cl[ni]) ? e : 0.f;
          capk[ni].x += e; capk[ni].y += ep;
        }
      }
    }
  }

  // Column partials -> LDS (4 quad slots per column), conflict-free stride.
  #pragma unroll
  for (int ni = 0; ni < 4; ++ni)
    colAP[(wn * 64 + ni * 16 + l15) * COL_STRIDE2 + quad] = capk[ni];

  __syncthreads();

  if (tid < 128) {
    // Column commit: sum 4 quad partials, one coalesced 64-lane atomic each.
    const float2* cp = &colAP[tid * COL_STRIDE2];
    float2 c0 = cp[0], c1 = cp[1], c2 = cp[2], c3 = cp[3];
    float sx = (c0.x + c1.x) + (c2.x + c3.x);
    float sy = (c0.y + c1.y) + (c2.y + c3.y);
    atomicAdd(&S_all[colBase + tid], sx);
    atomicAdd(&S_pos[colBase + tid], sy);
  } else if (offdiag) {
    // Row commit (== skipped transposed tile's columns): sum 16 lane partials.
    const int rr = tid - 128;
    const float2* rp = &rowAP[rr * ROW_STRIDE2];
    float sx = 0.f, sy = 0.f;
    #pragma unroll
    for (int i = 0; i < 16; ++i) { sx += rp[i].x; sy += rp[i].y; }
    atomicAdd(&S_all[rowBase + rr], sx);
    atomicAdd(&S_pos[rowBase + rr], sy);
  }
}

// Kernel 3: loss = sum_i log(S_all[i]) - log(S_pos[i])  (the +10 shifts cancel)
__global__ void __launch_bounds__(1024)
milnce_final(const float* __restrict__ S_all, const float* __restrict__ S_pos,
             float* __restrict__ out) {
  __shared__ float red[16];
  float s = 0.f;
  for (int i = threadIdx.x; i < NROWS; i += 1024)
    s += logf(S_all[i]) - logf(S_pos[i]);
  #pragma unroll
  for (int m = 1; m < 64; m <<= 1) s += __shfl_xor(s, m, 64);
  const int wave = threadIdx.x >> 6;
  if ((threadIdx.x & 63) == 0) red[wave] = s;
  __syncthreads();
  if (threadIdx.x == 0) {
    float t = 0.f;
    #pragma unroll
    for (int i = 0; i < 16; ++i) t += red[i];
    out[0] = t;
  }
}

extern "C" void kernel_launch(void* const* d_in, const int* in_sizes, int n_in,
                              void* d_out, int out_size, void* d_ws, size_t ws_size,
                              hipStream_t stream) {
  const float* feat   = (const float*)d_in[0];
  const float* pos    = (const float*)d_in[1];
  const int*   labels = (const int*)d_in[2];

  char* ws = (char*)d_ws;
  unsigned short* fb    = (unsigned short*)ws;                       // 4 MB bf16 concat
  float*          inv_w = (float*)(ws + 4u * 1024 * 1024);           // 32 KB
  int*            lab   = (int*)  (ws + 4u * 1024 * 1024 + 32 * 1024);
  float*          S_all = (float*)(ws + 4u * 1024 * 1024 + 64 * 1024);
  float*          S_pos = (float*)(ws + 4u * 1024 * 1024 + 96 * 1024);
  float*          out   = (float*)d_out;

  hipLaunchKernelGGL(milnce_prep, dim3(NROWS / 4), dim3(256), 0, stream,
                     feat, pos, labels, fb, inv_w, lab, S_all, S_pos);
  hipLaunchKernelGGL(milnce_gemm, dim3(NTRI), dim3(256), 0, stream,
                     fb, inv_w, lab, S_all, S_pos);
  hipLaunchKernelGGL(milnce_final, dim3(1), dim3(1024), 0, stream,
                     S_all, S_pos, out);
}